// Round 14
// baseline (190.023 us; speedup 1.0000x reference)
//
#include <hip/hip_runtime.h>
#include <hip/hip_bf16.h>
#include <math.h>

// Problem constants
#define DD 64
#define TT 128
#define BBATCH 32
#define BT (BBATCH*TT)         // 4096
#define ND 16                  // Delta truncation: (1-lam)^16 ~ 1.5e-5 for lam=0.5
#define BETA_C 0.8f
#define TWO_PI_R 6.28f         // repo uses 2*3.14
#define LG2_10000 13.28771237954945f
#define SW 328                 // f16 LDS row stride for prep staging
#define PST 72                 // E-phase psi LDS stride
#define NBLK 512u

typedef float2 cf;
typedef _Float16 f16;
typedef _Float16 half8 __attribute__((ext_vector_type(8)));
typedef _Float16 half4 __attribute__((ext_vector_type(4)));
typedef float f32x4 __attribute__((ext_vector_type(4)));

__device__ __forceinline__ void cfma(cf& acc, cf a, cf b){            // acc += a*b
  acc.x = fmaf(a.x, b.x, fmaf(-a.y, b.y, acc.x));
  acc.y = fmaf(a.x, b.y, fmaf( a.y, b.x, acc.y));
}

// Software grid barrier: counters zeroed by hipMemsetAsync before each launch.
// All 512 blocks are co-resident by construction (64KB LDS -> 2 blk/CU,
// launch_bounds(256,2) -> VGPR<=256 -> 2 blk/CU; 256 CU x 2 = 512 slots).
// Agent-scope acq/rel handles cross-XCD L2 non-coherence.
__device__ __forceinline__ void gbar(unsigned* c){
  __syncthreads();
  if (threadIdx.x == 0){
    __hip_atomic_fetch_add(c, 1u, __ATOMIC_ACQ_REL, __HIP_MEMORY_SCOPE_AGENT);
    while (__hip_atomic_load(c, __ATOMIC_ACQUIRE, __HIP_MEMORY_SCOPE_AGENT) < NBLK) {
      __builtin_amdgcn_s_sleep(1);
    }
  }
  __syncthreads();
}

// ---------------------------------------------------------------------------
// prep GEMM phase (R10/R12 proven)
// ---------------------------------------------------------------------------
template<int KDIM, int KPAD>
__device__ __forceinline__ f32x4 prep_phase(
    const float* __restrict__ Wp, const float* __restrict__ modg,
    f16* sWpT, f16* sMod, int tid, int w, int l15, int l4)
{
  __syncthreads();
  constexpr int PAD = KPAD - KDIM;
  for (int i = tid; i < 64*PAD; i += 256) {
    const int r = i / PAD, p = KDIM + (i - r*PAD);
    sWpT[r*SW + p] = (f16)0.f;
  }
  for (int i = tid; i < 16*PAD; i += 256) {
    const int r = i / PAD, p = KDIM + (i - r*PAD);
    sMod[r*SW + p] = (f16)0.f;
  }
  for (int i = tid; i < KDIM*16; i += 256) {
    const int p = i >> 4, c4 = (i & 15) << 2;
    const float4 v = *(const float4*)&Wp[p*64 + c4];
    sWpT[(c4+0)*SW + p] = (f16)v.x;
    sWpT[(c4+1)*SW + p] = (f16)v.y;
    sWpT[(c4+2)*SW + p] = (f16)v.z;
    sWpT[(c4+3)*SW + p] = (f16)v.w;
  }
  for (int i = tid; i < (16*KDIM)/4; i += 256) {
    const float4 v = *(const float4*)&modg[i*4];
    const float vv[4] = {v.x, v.y, v.z, v.w};
    #pragma unroll
    for (int e2 = 0; e2 < 4; ++e2) {
      const int flat = i*4 + e2;
      const int r = flat / KDIM, p = flat - r*KDIM;
      sMod[r*SW + p] = (f16)vv[e2];
    }
  }
  __syncthreads();
  f32x4 acc = {0.f, 0.f, 0.f, 0.f};
  #pragma unroll
  for (int s = 0; s < KPAD/32; ++s) {
    const half8 a = *(const half8*)&sWpT[(w*16 + l15)*SW + s*32 + l4*8];
    const half8 b = *(const half8*)&sMod[l15*SW + s*32 + l4*8];
    acc = __builtin_amdgcn_mfma_f32_16x16x32_f16(a, b, acc, 0, 0, 0);
  }
  return acc;
}

// ---------------------------------------------------------------------------
// Single kernel, 512 blocks x 256 threads, 3 phases + 2 software barriers:
//  A: blocks[0,64) TC power-chain; blocks[64,320) MFMA prep (R12 bodies)
//  B: all 512: E = sum_k |C psi_k|^2 (R12 k_E body)
//  C: all 512: Delta-conv + identity + head (R12 k_head x 8 bt)
// ---------------------------------------------------------------------------
__global__ __launch_bounds__(256, 2) void k_all(
    const float* __restrict__ mod0, const float* __restrict__ Wp0, const float* __restrict__ bp0,
    const float* __restrict__ mod1, const float* __restrict__ Wp1, const float* __restrict__ bp1,
    const float* __restrict__ mod2, const float* __restrict__ Wp2, const float* __restrict__ bp2,
    const float* __restrict__ smask, const float* __restrict__ ptab,
    const float* __restrict__ Uhr, const float* __restrict__ Uhi,
    const float* __restrict__ Uxr, const float* __restrict__ Uxi,
    const float* __restrict__ Kr,  const float* __restrict__ Ki,
    const float* __restrict__ Lam,
    const float* __restrict__ W1, const float* __restrict__ b1,
    const float* __restrict__ W2, const float* __restrict__ b2,
    f16* __restrict__ PsiR, f16* __restrict__ PsiI,
    f16* __restrict__ Cre, f16* __restrict__ Cim, f16* __restrict__ Cmn,
    float* __restrict__ kn, f16* __restrict__ e16,
    unsigned* __restrict__ bar0, unsigned* __restrict__ bar1,
    float* __restrict__ out)
{
  __shared__ __align__(16) char smem[65536];
  const int bid = blockIdx.x;
  const int tid = threadIdx.x, w = tid >> 6, lane = tid & 63;
  const int l15 = lane & 15, l4 = lane >> 4;

  // ================= Phase A: TC (bid<64) | prep (64<=bid<320) ==========
  if (bid < 64) {
    cf* st = (cf*)smem;                         // [64]
    cf (*red)[64] = (cf(*)[64])(smem + 512);    // [8][64]
    const int j = bid, c = lane;

    cf uh[16], ux[16];
    #pragma unroll
    for (int i = 0; i < 16; ++i) {
      const int p = w*16 + i;
      uh[i] = make_float2(Uhr[p*64 + c], Uhi[p*64 + c]);
      ux[i] = make_float2(Uxr[p*64 + c], Uxi[p*64 + c]);
    }
    if (w == 0) {
      const cf kj = make_float2(Kr[j*64 + c], -Ki[j*64 + c]);
      st[c] = kj;
      float q = fmaf(kj.x, kj.x, kj.y*kj.y);
      #pragma unroll
      for (int off = 32; off; off >>= 1) q += __shfl_xor(q, off);
      if (c == 0) kn[j] = q;
    }
    __syncthreads();

    for (int D = 0; D < ND; ++D) {
      cf cA = {0.f,0.f}, cB = {0.f,0.f}, tA = {0.f,0.f}, tB = {0.f,0.f};
      #pragma unroll
      for (int i = 0; i < 16; i += 2) {
        const cf t0 = st[w*16 + i], t1 = st[w*16 + i + 1];
        cfma(cA, t0, ux[i]); cfma(cB, t1, ux[i+1]);
        cfma(tA, t0, uh[i]); cfma(tB, t1, uh[i+1]);
      }
      red[w][c]     = make_float2(cA.x + cB.x, cA.y + cB.y);
      red[4 + w][c] = make_float2(tA.x + tB.x, tA.y + tB.y);
      __syncthreads();
      if (w == 0) {
        const cf r0 = red[0][c], r1 = red[1][c], r2 = red[2][c], r3 = red[3][c];
        const float crx = r0.x + r1.x + r2.x + r3.x;
        const float cry = r0.y + r1.y + r2.y + r3.y;
        const size_t row = (size_t)(D*64 + j)*64 + c;
        Cre[row] = (f16)crx;
        Cim[row] = (f16)cry;
        Cmn[row] = (f16)(-cry);
      } else if (w == 1) {
        const cf r0 = red[4][c], r1 = red[5][c], r2 = red[6][c], r3 = red[7][c];
        st[c] = make_float2(r0.x + r1.x + r2.x + r3.x, r0.y + r1.y + r2.y + r3.y);
      }
      __syncthreads();
    }
  } else if (bid < 320) {
    f16* sWpT = (f16*)smem;                        // [64][SW]
    f16* sMod = (f16*)(smem + 41984);              // [16][SW]
    float* repS = (float*)(smem + 52480);          // [3][16][68]
    const int bt0 = (bid - 64) * 16;

    const f32x4 a0 = prep_phase<300,320>(Wp0, mod0 + (size_t)bt0*300, sWpT, sMod, tid, w, l15, l4);
    #pragma unroll
    for (int r = 0; r < 4; ++r) {
      const int d = w*16 + l4*4 + r;
      repS[(0*16 + l15)*68 + d] = a0[r] + bp0[d];
    }
    const f32x4 a1 = prep_phase<74,96>(Wp1, mod1 + (size_t)bt0*74, sWpT, sMod, tid, w, l15, l4);
    #pragma unroll
    for (int r = 0; r < 4; ++r) {
      const int d = w*16 + l4*4 + r;
      repS[(1*16 + l15)*68 + d] = a1[r] + bp1[d];
    }
    const f32x4 a2 = prep_phase<35,64>(Wp2, mod2 + (size_t)bt0*35, sWpT, sMod, tid, w, l15, l4);
    #pragma unroll
    for (int r = 0; r < 4; ++r) {
      const int d = w*16 + l4*4 + r;
      repS[(2*16 + l15)*68 + d] = a2[r] + bp2[d];
    }
    __syncthreads();

    const int btl = tid >> 4, g = tid & 15;
    float4 v0 = *(float4*)&repS[(0*16 + btl)*68 + g*4];
    float4 v1 = *(float4*)&repS[(1*16 + btl)*68 + g*4];
    float4 v2 = *(float4*)&repS[(2*16 + btl)*68 + g*4];
    v0.x = fmaxf(v0.x, 0.f); v0.y = fmaxf(v0.y, 0.f); v0.z = fmaxf(v0.z, 0.f); v0.w = fmaxf(v0.w, 0.f);
    v1.x = fmaxf(v1.x, 0.f); v1.y = fmaxf(v1.y, 0.f); v1.z = fmaxf(v1.z, 0.f); v1.w = fmaxf(v1.w, 0.f);
    v2.x = fmaxf(v2.x, 0.f); v2.y = fmaxf(v2.y, 0.f); v2.z = fmaxf(v2.z, 0.f); v2.w = fmaxf(v2.w, 0.f);

    float q0 = v0.x*v0.x + v0.y*v0.y + v0.z*v0.z + v0.w*v0.w;
    float q1 = v1.x*v1.x + v1.y*v1.y + v1.z*v1.z + v1.w*v1.w;
    float q2 = v2.x*v2.x + v2.y*v2.y + v2.z*v2.z + v2.w*v2.w;
    #pragma unroll
    for (int off = 8; off; off >>= 1) {
      q0 += __shfl_xor(q0, off);
      q1 += __shfl_xor(q1, off);
      q2 += __shfl_xor(q2, off);
    }
    const float n0 = sqrtf(q0), n1 = sqrtf(q1), n2 = sqrtf(q2);
    const float mx = fmaxf(n0, fmaxf(n1, n2));
    const float e0 = expf(n0 - mx), e1 = expf(n1 - mx), e2 = expf(n2 - mx);
    const float inv = 1.f / (e0 + e1 + e2);
    const float sc0 = sqrtf(e0*inv) / fmaxf(n0, 1e-12f);
    const float sc1 = sqrtf(e1*inv) / fmaxf(n1, 1e-12f);
    const float sc2 = sqrtf(e2*inv) / fmaxf(n2, 1e-12f);

    const int btg = bt0 + btl;
    const int t = btg & (TT-1);
    const int sid = (smask[btg*2 + 1] > smask[btg*2]) ? 1 : 0;

    float cs[4], sn[4];
    #pragma unroll
    for (int i = 0; i < 4; ++i) {
      const int d = g*4 + i;
      const float freq = exp2f(-((float)d * (1.f/64.f)) * LG2_10000);
      const float ph = (float)t * freq + ptab[sid*64 + d] * TWO_PI_R;
      sincosf(ph, &sn[i], &cs[i]);
    }
    const float am0[4] = {v0.x*sc0, v0.y*sc0, v0.z*sc0, v0.w*sc0};
    const float am1[4] = {v1.x*sc1, v1.y*sc1, v1.z*sc1, v1.w*sc1};
    const float am2[4] = {v2.x*sc2, v2.y*sc2, v2.z*sc2, v2.w*sc2};
    half4 wr, wi;
    #pragma unroll
    for (int i = 0; i < 4; ++i) { wr[i] = (f16)(am0[i]*cs[i]); wi[i] = (f16)(am0[i]*sn[i]); }
    *(half4*)&PsiR[(size_t)(0*BT + btg)*64 + g*4] = wr;
    *(half4*)&PsiI[(size_t)(0*BT + btg)*64 + g*4] = wi;
    #pragma unroll
    for (int i = 0; i < 4; ++i) { wr[i] = (f16)(am1[i]*cs[i]); wi[i] = (f16)(am1[i]*sn[i]); }
    *(half4*)&PsiR[(size_t)(1*BT + btg)*64 + g*4] = wr;
    *(half4*)&PsiI[(size_t)(1*BT + btg)*64 + g*4] = wi;
    #pragma unroll
    for (int i = 0; i < 4; ++i) { wr[i] = (f16)(am2[i]*cs[i]); wi[i] = (f16)(am2[i]*sn[i]); }
    *(half4*)&PsiR[(size_t)(2*BT + btg)*64 + g*4] = wr;
    *(half4*)&PsiI[(size_t)(2*BT + btg)*64 + g*4] = wi;
  }
  gbar(bar0);

  // ================= Phase B: E (all 512 blocks) ========================
  {
    f16 (*sP)[2][64][PST] = (f16(*)[2][64][PST])smem;   // [2][2][64][PST] = 36864 B
    const int bsg = bid >> 3, cgg = bid & 7;

    half8 aRe[2][2], aIm[2][2], aMn[2][2];
    #pragma unroll
    for (int cc = 0; cc < 2; ++cc) {
      const size_t arow = ((size_t)((cgg*2 + cc)*64 + w*16 + l15))*64 + l4*8;
      aRe[cc][0] = *(const half8*)&Cre[arow]; aRe[cc][1] = *(const half8*)&Cre[arow + 32];
      aIm[cc][0] = *(const half8*)&Cim[arow]; aIm[cc][1] = *(const half8*)&Cim[arow + 32];
      aMn[cc][0] = *(const half8*)&Cmn[arow]; aMn[cc][1] = *(const half8*)&Cmn[arow + 32];
    }

    const int r0s = tid >> 3, c8s = (tid & 7) << 3;
    const int r1s = (tid + 256) >> 3;
    {
      const size_t g0 = ((size_t)(0*BT + bsg*64 + r0s))*64 + c8s;
      const size_t g1 = ((size_t)(0*BT + bsg*64 + r1s))*64 + c8s;
      *(uint4*)&sP[0][0][r0s][c8s] = *(const uint4*)&PsiR[g0];
      *(uint4*)&sP[0][1][r0s][c8s] = *(const uint4*)&PsiI[g0];
      *(uint4*)&sP[0][0][r1s][c8s] = *(const uint4*)&PsiR[g1];
      *(uint4*)&sP[0][1][r1s][c8s] = *(const uint4*)&PsiI[g1];
    }

    f32x4 eAcc[2][4];
    #pragma unroll
    for (int cc = 0; cc < 2; ++cc)
      #pragma unroll
      for (int ct = 0; ct < 4; ++ct) eAcc[cc][ct] = (f32x4){0.f,0.f,0.f,0.f};

    #pragma unroll
    for (int k = 0; k < 3; ++k) {
      uint4 nR0, nI0, nR1, nI1;
      if (k < 2) {
        const size_t g0 = ((size_t)((k+1)*BT + bsg*64 + r0s))*64 + c8s;
        const size_t g1 = ((size_t)((k+1)*BT + bsg*64 + r1s))*64 + c8s;
        nR0 = *(const uint4*)&PsiR[g0];
        nI0 = *(const uint4*)&PsiI[g0];
        nR1 = *(const uint4*)&PsiR[g1];
        nI1 = *(const uint4*)&PsiI[g1];
      }
      __syncthreads();
      const int kb = k & 1;
      #pragma unroll
      for (int cc = 0; cc < 2; ++cc) {
        #pragma unroll
        for (int ct = 0; ct < 4; ++ct) {
          f32x4 xr = {0.f,0.f,0.f,0.f}, xi = {0.f,0.f,0.f,0.f};
          #pragma unroll
          for (int kk = 0; kk < 2; ++kk) {
            const half8 bRe = *(const half8*)&sP[kb][0][ct*16 + l15][l4*8 + kk*32];
            const half8 bIm = *(const half8*)&sP[kb][1][ct*16 + l15][l4*8 + kk*32];
            xr = __builtin_amdgcn_mfma_f32_16x16x32_f16(aRe[cc][kk], bRe, xr, 0, 0, 0);
            xr = __builtin_amdgcn_mfma_f32_16x16x32_f16(aMn[cc][kk], bIm, xr, 0, 0, 0);
            xi = __builtin_amdgcn_mfma_f32_16x16x32_f16(aRe[cc][kk], bIm, xi, 0, 0, 0);
            xi = __builtin_amdgcn_mfma_f32_16x16x32_f16(aIm[cc][kk], bRe, xi, 0, 0, 0);
          }
          #pragma unroll
          for (int r = 0; r < 4; ++r)
            eAcc[cc][ct][r] = fmaf(xr[r], xr[r], fmaf(xi[r], xi[r], eAcc[cc][ct][r]));
        }
      }
      if (k < 2) {
        const int nb = kb ^ 1;
        *(uint4*)&sP[nb][0][r0s][c8s] = nR0;
        *(uint4*)&sP[nb][1][r0s][c8s] = nI0;
        *(uint4*)&sP[nb][0][r1s][c8s] = nR1;
        *(uint4*)&sP[nb][1][r1s][c8s] = nI1;
      }
    }

    f16* sE = (f16*)smem;
    #pragma unroll
    for (int cc = 0; cc < 2; ++cc) {
      __syncthreads();
      #pragma unroll
      for (int ct = 0; ct < 4; ++ct)
        #pragma unroll
        for (int r = 0; r < 4; ++r)
          sE[(ct*16 + l15)*PST + w*16 + l4*4 + r] = (f16)eAcc[cc][ct][r];
      __syncthreads();
      const int cg = cgg*2 + cc;
      *(uint4*)&e16[((size_t)(bsg*64 + r0s))*1024 + cg*64 + c8s] = *(const uint4*)&sE[r0s*PST + c8s];
      *(uint4*)&e16[((size_t)(bsg*64 + r1s))*1024 + cg*64 + c8s] = *(const uint4*)&sE[r1s*PST + c8s];
    }
  }
  gbar(bar1);

  // ================= Phase C: head (all 512 blocks, 8 bt each) ==========
  {
    float* sW1 = (float*)smem;                 // 16384 B
    float (*pr)[64] = (float(*)[64])(smem + 16384);
    float (*h1)[64] = (float(*)[64])(smem + 17408);
    float (*lg)[8]  = (float(*)[8]) (smem + 18432);
    const int q = tid >> 6, j = tid & 63;
    const float lam = Lam[0], om = 1.f - lam;
    const float l2om = log2f(om);

    for (int i = tid*4; i < 4096; i += 1024)
      *(float4*)&sW1[i] = *(const float4*)&W1[i];

    #pragma unroll
    for (int ii = 0; ii < 2; ++ii) {
      const int bt = bid*8 + ii*4 + q;
      const int b = bt >> 7, t = bt & (TT-1);

      float acc = 0.f, wD = BETA_C * lam;
      const int nd = min(ND, t + 1);
      for (int D = 0; D < nd; ++D) {
        acc += wD * (float)e16[(size_t)(b*TT + t - D)*1024 + D*64 + j];
        wD *= om;
      }
      const float omt = exp2f((float)(t + 1) * l2om);
      acc += (BETA_C*omt + (1.f - BETA_C)) * kn[j] * (1.f/64.f);
      pr[q][j] = acc;
      __syncthreads();

      float a1 = b1[j];
      for (int dd = 0; dd < 64; ++dd) a1 = fmaf(pr[q][dd], sW1[dd*64 + j], a1);
      h1[q][j] = fmaxf(a1, 0.f);
      __syncthreads();

      if (j < 6) {
        float a2 = b2[j];
        for (int c = 0; c < 64; ++c) a2 = fmaf(h1[q][c], W2[c*6 + j], a2);
        lg[q][j] = tanhf(a2);
      }
      __syncthreads();
      if (j < 6) {
        float mxv = -1e30f;
        #pragma unroll
        for (int n = 0; n < 6; ++n) mxv = fmaxf(mxv, lg[q][n]);
        float se = 0.f;
        #pragma unroll
        for (int n = 0; n < 6; ++n) se += expf(lg[q][n] - mxv);
        out[bt*6 + j] = lg[q][j] - mxv - logf(se);
      }
      __syncthreads();
    }
  }
}

// ---------------------------------------------------------------------------
extern "C" void kernel_launch(void* const* d_in, const int* in_sizes, int n_in,
                              void* d_out, int out_size, void* d_ws, size_t ws_size,
                              hipStream_t stream)
{
  const float* mod0  = (const float*)d_in[0];
  const float* Wp0   = (const float*)d_in[1];
  const float* bp0   = (const float*)d_in[2];
  const float* mod1  = (const float*)d_in[3];
  const float* Wp1   = (const float*)d_in[4];
  const float* bp1   = (const float*)d_in[5];
  const float* mod2  = (const float*)d_in[6];
  const float* Wp2   = (const float*)d_in[7];
  const float* bp2   = (const float*)d_in[8];
  const float* smask = (const float*)d_in[9];
  const float* ptab  = (const float*)d_in[11];
  const float* Uhr   = (const float*)d_in[12];
  const float* Uhi   = (const float*)d_in[13];
  const float* Uxr   = (const float*)d_in[14];
  const float* Uxi   = (const float*)d_in[15];
  const float* Lam   = (const float*)d_in[16];
  const float* Kr    = (const float*)d_in[17];
  const float* Ki    = (const float*)d_in[18];
  const float* W1    = (const float*)d_in[19];
  const float* b1    = (const float*)d_in[20];
  const float* W2    = (const float*)d_in[21];
  const float* b2    = (const float*)d_in[22];

  char* ws = (char*)d_ws;
  float*    kn   = (float*)(ws);                        // 256 B
  unsigned* bar0 = (unsigned*)(ws + 4096);
  unsigned* bar1 = (unsigned*)(ws + 4224);
  f16*      Cre  = (f16*)(ws + ((size_t)1024 << 10));   // 128KB each
  f16*      Cim  = (f16*)(ws + ((size_t)1280 << 10));
  f16*      Cmn  = (f16*)(ws + ((size_t)1536 << 10));
  f16*      PsiR = (f16*)(ws + ((size_t)2 << 20));      // 512KB each
  f16*      PsiI = (f16*)(ws + ((size_t)4 << 20));
  f16*      e16  = (f16*)(ws + ((size_t)6 << 20));      // 8.4MB
  if (ws_size < ((size_t)16 << 20)) return;

  // zero the two barrier counters each call (capture-safe async memset)
  hipMemsetAsync(ws + 4096, 0, 256, stream);

  k_all<<<512, 256, 0, stream>>>(mod0, Wp0, bp0, mod1, Wp1, bp1, mod2, Wp2, bp2,
                                 smask, ptab, Uhr, Uhi, Uxr, Uxi, Kr, Ki, Lam,
                                 W1, b1, W2, b2, PsiR, PsiI, Cre, Cim, Cmn,
                                 kn, e16, bar0, bar1, (float*)d_out);
}

// Round 15
// 128.763 us; speedup vs baseline: 1.4758x; 1.4758x over previous
//
#include <hip/hip_runtime.h>
#include <hip/hip_bf16.h>
#include <math.h>

// Problem constants
#define DD 64
#define TT 128
#define BBATCH 32
#define BT (BBATCH*TT)         // 4096
#define ND 16                  // Delta truncation: (1-lam)^16 ~ 1.5e-5 for lam=0.5
#define BETA_C 0.8f
#define TWO_PI_R 6.28f         // repo uses 2*3.14
#define LG2_10000 13.28771237954945f
#define SW 328                 // f16 LDS row stride for prep staging
#define PST 72                 // E-phase psi LDS stride
#define NBLK 512u

typedef float2 cf;
typedef _Float16 f16;
typedef _Float16 half8 __attribute__((ext_vector_type(8)));
typedef _Float16 half4 __attribute__((ext_vector_type(4)));
typedef float f32x4 __attribute__((ext_vector_type(4)));

__device__ __forceinline__ void cfma(cf& acc, cf a, cf b){            // acc += a*b
  acc.x = fmaf(a.x, b.x, fmaf(-a.y, b.y, acc.x));
  acc.y = fmaf(a.x, b.y, fmaf( a.y, b.x, acc.y));
}

// Software grid barrier v2. R14's version spun on ACQUIRE loads: every poll
// emits an L1+L2 invalidate (buffer_inv) -> 512 spinners produced a cache-
// invalidation storm that slowed straggler phases to HBM latency (190us).
// v2: RELAXED spin (coherent LLC read, no invalidate) + s_sleep(16) backoff,
// acquire fallback every 32nd poll (hang-proof), one final ACQUIRE at exit
// (the mandatory invalidate so this block sees remote writes / no stale L2).
__device__ __forceinline__ void gbar(unsigned* c){
  __syncthreads();
  if (threadIdx.x == 0){
    __hip_atomic_fetch_add(c, 1u, __ATOMIC_RELEASE, __HIP_MEMORY_SCOPE_AGENT);
    unsigned v = __hip_atomic_load(c, __ATOMIC_ACQUIRE, __HIP_MEMORY_SCOPE_AGENT);
    unsigned spins = 0;
    while (v < NBLK) {
      __builtin_amdgcn_s_sleep(16);
      v = ((++spins) & 31u)
            ? __hip_atomic_load(c, __ATOMIC_RELAXED, __HIP_MEMORY_SCOPE_AGENT)
            : __hip_atomic_load(c, __ATOMIC_ACQUIRE, __HIP_MEMORY_SCOPE_AGENT);
    }
    (void)__hip_atomic_load(c, __ATOMIC_ACQUIRE, __HIP_MEMORY_SCOPE_AGENT);
  }
  __syncthreads();
}

// ---------------------------------------------------------------------------
// prep GEMM phase (R10/R12 proven)
// ---------------------------------------------------------------------------
template<int KDIM, int KPAD>
__device__ __forceinline__ f32x4 prep_phase(
    const float* __restrict__ Wp, const float* __restrict__ modg,
    f16* sWpT, f16* sMod, int tid, int w, int l15, int l4)
{
  __syncthreads();
  constexpr int PAD = KPAD - KDIM;
  for (int i = tid; i < 64*PAD; i += 256) {
    const int r = i / PAD, p = KDIM + (i - r*PAD);
    sWpT[r*SW + p] = (f16)0.f;
  }
  for (int i = tid; i < 16*PAD; i += 256) {
    const int r = i / PAD, p = KDIM + (i - r*PAD);
    sMod[r*SW + p] = (f16)0.f;
  }
  for (int i = tid; i < KDIM*16; i += 256) {
    const int p = i >> 4, c4 = (i & 15) << 2;
    const float4 v = *(const float4*)&Wp[p*64 + c4];
    sWpT[(c4+0)*SW + p] = (f16)v.x;
    sWpT[(c4+1)*SW + p] = (f16)v.y;
    sWpT[(c4+2)*SW + p] = (f16)v.z;
    sWpT[(c4+3)*SW + p] = (f16)v.w;
  }
  for (int i = tid; i < (16*KDIM)/4; i += 256) {
    const float4 v = *(const float4*)&modg[i*4];
    const float vv[4] = {v.x, v.y, v.z, v.w};
    #pragma unroll
    for (int e2 = 0; e2 < 4; ++e2) {
      const int flat = i*4 + e2;
      const int r = flat / KDIM, p = flat - r*KDIM;
      sMod[r*SW + p] = (f16)vv[e2];
    }
  }
  __syncthreads();
  f32x4 acc = {0.f, 0.f, 0.f, 0.f};
  #pragma unroll
  for (int s = 0; s < KPAD/32; ++s) {
    const half8 a = *(const half8*)&sWpT[(w*16 + l15)*SW + s*32 + l4*8];
    const half8 b = *(const half8*)&sMod[l15*SW + s*32 + l4*8];
    acc = __builtin_amdgcn_mfma_f32_16x16x32_f16(a, b, acc, 0, 0, 0);
  }
  return acc;
}

// ---------------------------------------------------------------------------
// Single kernel, 512 blocks x 256 threads, 3 phases + 2 software barriers:
//  A: blocks[0,64) TC power-chain; blocks[64,320) MFMA prep (R12 bodies)
//  B: all 512: E = sum_k |C psi_k|^2 (R12 k_E body)
//  C: all 512: Delta-conv + identity + head (R12 k_head x 8 bt)
// ---------------------------------------------------------------------------
__global__ __launch_bounds__(256, 2) void k_all(
    const float* __restrict__ mod0, const float* __restrict__ Wp0, const float* __restrict__ bp0,
    const float* __restrict__ mod1, const float* __restrict__ Wp1, const float* __restrict__ bp1,
    const float* __restrict__ mod2, const float* __restrict__ Wp2, const float* __restrict__ bp2,
    const float* __restrict__ smask, const float* __restrict__ ptab,
    const float* __restrict__ Uhr, const float* __restrict__ Uhi,
    const float* __restrict__ Uxr, const float* __restrict__ Uxi,
    const float* __restrict__ Kr,  const float* __restrict__ Ki,
    const float* __restrict__ Lam,
    const float* __restrict__ W1, const float* __restrict__ b1,
    const float* __restrict__ W2, const float* __restrict__ b2,
    f16* __restrict__ PsiR, f16* __restrict__ PsiI,
    f16* __restrict__ Cre, f16* __restrict__ Cim, f16* __restrict__ Cmn,
    float* __restrict__ kn, f16* __restrict__ e16,
    unsigned* __restrict__ bar0, unsigned* __restrict__ bar1,
    float* __restrict__ out)
{
  __shared__ __align__(16) char smem[65536];
  const int bid = blockIdx.x;
  const int tid = threadIdx.x, w = tid >> 6, lane = tid & 63;
  const int l15 = lane & 15, l4 = lane >> 4;

  // ================= Phase A: TC (bid<64) | prep (64<=bid<320) ==========
  if (bid < 64) {
    cf* st = (cf*)smem;                         // [64]
    cf (*red)[64] = (cf(*)[64])(smem + 512);    // [8][64]
    const int j = bid, c = lane;

    cf uh[16], ux[16];
    #pragma unroll
    for (int i = 0; i < 16; ++i) {
      const int p = w*16 + i;
      uh[i] = make_float2(Uhr[p*64 + c], Uhi[p*64 + c]);
      ux[i] = make_float2(Uxr[p*64 + c], Uxi[p*64 + c]);
    }
    if (w == 0) {
      const cf kj = make_float2(Kr[j*64 + c], -Ki[j*64 + c]);
      st[c] = kj;
      float q = fmaf(kj.x, kj.x, kj.y*kj.y);
      #pragma unroll
      for (int off = 32; off; off >>= 1) q += __shfl_xor(q, off);
      if (c == 0) kn[j] = q;
    }
    __syncthreads();

    for (int D = 0; D < ND; ++D) {
      cf cA = {0.f,0.f}, cB = {0.f,0.f}, tA = {0.f,0.f}, tB = {0.f,0.f};
      #pragma unroll
      for (int i = 0; i < 16; i += 2) {
        const cf t0 = st[w*16 + i], t1 = st[w*16 + i + 1];
        cfma(cA, t0, ux[i]); cfma(cB, t1, ux[i+1]);
        cfma(tA, t0, uh[i]); cfma(tB, t1, uh[i+1]);
      }
      red[w][c]     = make_float2(cA.x + cB.x, cA.y + cB.y);
      red[4 + w][c] = make_float2(tA.x + tB.x, tA.y + tB.y);
      __syncthreads();
      if (w == 0) {
        const cf r0 = red[0][c], r1 = red[1][c], r2 = red[2][c], r3 = red[3][c];
        const float crx = r0.x + r1.x + r2.x + r3.x;
        const float cry = r0.y + r1.y + r2.y + r3.y;
        const size_t row = (size_t)(D*64 + j)*64 + c;
        Cre[row] = (f16)crx;
        Cim[row] = (f16)cry;
        Cmn[row] = (f16)(-cry);
      } else if (w == 1) {
        const cf r0 = red[4][c], r1 = red[5][c], r2 = red[6][c], r3 = red[7][c];
        st[c] = make_float2(r0.x + r1.x + r2.x + r3.x, r0.y + r1.y + r2.y + r3.y);
      }
      __syncthreads();
    }
  } else if (bid < 320) {
    f16* sWpT = (f16*)smem;                        // [64][SW]
    f16* sMod = (f16*)(smem + 41984);              // [16][SW]
    float* repS = (float*)(smem + 52480);          // [3][16][68]
    const int bt0 = (bid - 64) * 16;

    const f32x4 a0 = prep_phase<300,320>(Wp0, mod0 + (size_t)bt0*300, sWpT, sMod, tid, w, l15, l4);
    #pragma unroll
    for (int r = 0; r < 4; ++r) {
      const int d = w*16 + l4*4 + r;
      repS[(0*16 + l15)*68 + d] = a0[r] + bp0[d];
    }
    const f32x4 a1 = prep_phase<74,96>(Wp1, mod1 + (size_t)bt0*74, sWpT, sMod, tid, w, l15, l4);
    #pragma unroll
    for (int r = 0; r < 4; ++r) {
      const int d = w*16 + l4*4 + r;
      repS[(1*16 + l15)*68 + d] = a1[r] + bp1[d];
    }
    const f32x4 a2 = prep_phase<35,64>(Wp2, mod2 + (size_t)bt0*35, sWpT, sMod, tid, w, l15, l4);
    #pragma unroll
    for (int r = 0; r < 4; ++r) {
      const int d = w*16 + l4*4 + r;
      repS[(2*16 + l15)*68 + d] = a2[r] + bp2[d];
    }
    __syncthreads();

    const int btl = tid >> 4, g = tid & 15;
    float4 v0 = *(float4*)&repS[(0*16 + btl)*68 + g*4];
    float4 v1 = *(float4*)&repS[(1*16 + btl)*68 + g*4];
    float4 v2 = *(float4*)&repS[(2*16 + btl)*68 + g*4];
    v0.x = fmaxf(v0.x, 0.f); v0.y = fmaxf(v0.y, 0.f); v0.z = fmaxf(v0.z, 0.f); v0.w = fmaxf(v0.w, 0.f);
    v1.x = fmaxf(v1.x, 0.f); v1.y = fmaxf(v1.y, 0.f); v1.z = fmaxf(v1.z, 0.f); v1.w = fmaxf(v1.w, 0.f);
    v2.x = fmaxf(v2.x, 0.f); v2.y = fmaxf(v2.y, 0.f); v2.z = fmaxf(v2.z, 0.f); v2.w = fmaxf(v2.w, 0.f);

    float q0 = v0.x*v0.x + v0.y*v0.y + v0.z*v0.z + v0.w*v0.w;
    float q1 = v1.x*v1.x + v1.y*v1.y + v1.z*v1.z + v1.w*v1.w;
    float q2 = v2.x*v2.x + v2.y*v2.y + v2.z*v2.z + v2.w*v2.w;
    #pragma unroll
    for (int off = 8; off; off >>= 1) {
      q0 += __shfl_xor(q0, off);
      q1 += __shfl_xor(q1, off);
      q2 += __shfl_xor(q2, off);
    }
    const float n0 = sqrtf(q0), n1 = sqrtf(q1), n2 = sqrtf(q2);
    const float mx = fmaxf(n0, fmaxf(n1, n2));
    const float e0 = expf(n0 - mx), e1 = expf(n1 - mx), e2 = expf(n2 - mx);
    const float inv = 1.f / (e0 + e1 + e2);
    const float sc0 = sqrtf(e0*inv) / fmaxf(n0, 1e-12f);
    const float sc1 = sqrtf(e1*inv) / fmaxf(n1, 1e-12f);
    const float sc2 = sqrtf(e2*inv) / fmaxf(n2, 1e-12f);

    const int btg = bt0 + btl;
    const int t = btg & (TT-1);
    const int sid = (smask[btg*2 + 1] > smask[btg*2]) ? 1 : 0;

    float cs[4], sn[4];
    #pragma unroll
    for (int i = 0; i < 4; ++i) {
      const int d = g*4 + i;
      const float freq = exp2f(-((float)d * (1.f/64.f)) * LG2_10000);
      const float ph = (float)t * freq + ptab[sid*64 + d] * TWO_PI_R;
      sincosf(ph, &sn[i], &cs[i]);
    }
    const float am0[4] = {v0.x*sc0, v0.y*sc0, v0.z*sc0, v0.w*sc0};
    const float am1[4] = {v1.x*sc1, v1.y*sc1, v1.z*sc1, v1.w*sc1};
    const float am2[4] = {v2.x*sc2, v2.y*sc2, v2.z*sc2, v2.w*sc2};
    half4 wr, wi;
    #pragma unroll
    for (int i = 0; i < 4; ++i) { wr[i] = (f16)(am0[i]*cs[i]); wi[i] = (f16)(am0[i]*sn[i]); }
    *(half4*)&PsiR[(size_t)(0*BT + btg)*64 + g*4] = wr;
    *(half4*)&PsiI[(size_t)(0*BT + btg)*64 + g*4] = wi;
    #pragma unroll
    for (int i = 0; i < 4; ++i) { wr[i] = (f16)(am1[i]*cs[i]); wi[i] = (f16)(am1[i]*sn[i]); }
    *(half4*)&PsiR[(size_t)(1*BT + btg)*64 + g*4] = wr;
    *(half4*)&PsiI[(size_t)(1*BT + btg)*64 + g*4] = wi;
    #pragma unroll
    for (int i = 0; i < 4; ++i) { wr[i] = (f16)(am2[i]*cs[i]); wi[i] = (f16)(am2[i]*sn[i]); }
    *(half4*)&PsiR[(size_t)(2*BT + btg)*64 + g*4] = wr;
    *(half4*)&PsiI[(size_t)(2*BT + btg)*64 + g*4] = wi;
  }
  gbar(bar0);

  // ================= Phase B: E (all 512 blocks) ========================
  {
    f16 (*sP)[2][64][PST] = (f16(*)[2][64][PST])smem;   // [2][2][64][PST] = 36864 B
    const int bsg = bid >> 3, cgg = bid & 7;

    half8 aRe[2][2], aIm[2][2], aMn[2][2];
    #pragma unroll
    for (int cc = 0; cc < 2; ++cc) {
      const size_t arow = ((size_t)((cgg*2 + cc)*64 + w*16 + l15))*64 + l4*8;
      aRe[cc][0] = *(const half8*)&Cre[arow]; aRe[cc][1] = *(const half8*)&Cre[arow + 32];
      aIm[cc][0] = *(const half8*)&Cim[arow]; aIm[cc][1] = *(const half8*)&Cim[arow + 32];
      aMn[cc][0] = *(const half8*)&Cmn[arow]; aMn[cc][1] = *(const half8*)&Cmn[arow + 32];
    }

    const int r0s = tid >> 3, c8s = (tid & 7) << 3;
    const int r1s = (tid + 256) >> 3;
    {
      const size_t g0 = ((size_t)(0*BT + bsg*64 + r0s))*64 + c8s;
      const size_t g1 = ((size_t)(0*BT + bsg*64 + r1s))*64 + c8s;
      *(uint4*)&sP[0][0][r0s][c8s] = *(const uint4*)&PsiR[g0];
      *(uint4*)&sP[0][1][r0s][c8s] = *(const uint4*)&PsiI[g0];
      *(uint4*)&sP[0][0][r1s][c8s] = *(const uint4*)&PsiR[g1];
      *(uint4*)&sP[0][1][r1s][c8s] = *(const uint4*)&PsiI[g1];
    }

    f32x4 eAcc[2][4];
    #pragma unroll
    for (int cc = 0; cc < 2; ++cc)
      #pragma unroll
      for (int ct = 0; ct < 4; ++ct) eAcc[cc][ct] = (f32x4){0.f,0.f,0.f,0.f};

    #pragma unroll
    for (int k = 0; k < 3; ++k) {
      uint4 nR0, nI0, nR1, nI1;
      if (k < 2) {
        const size_t g0 = ((size_t)((k+1)*BT + bsg*64 + r0s))*64 + c8s;
        const size_t g1 = ((size_t)((k+1)*BT + bsg*64 + r1s))*64 + c8s;
        nR0 = *(const uint4*)&PsiR[g0];
        nI0 = *(const uint4*)&PsiI[g0];
        nR1 = *(const uint4*)&PsiR[g1];
        nI1 = *(const uint4*)&PsiI[g1];
      }
      __syncthreads();
      const int kb = k & 1;
      #pragma unroll
      for (int cc = 0; cc < 2; ++cc) {
        #pragma unroll
        for (int ct = 0; ct < 4; ++ct) {
          f32x4 xr = {0.f,0.f,0.f,0.f}, xi = {0.f,0.f,0.f,0.f};
          #pragma unroll
          for (int kk = 0; kk < 2; ++kk) {
            const half8 bRe = *(const half8*)&sP[kb][0][ct*16 + l15][l4*8 + kk*32];
            const half8 bIm = *(const half8*)&sP[kb][1][ct*16 + l15][l4*8 + kk*32];
            xr = __builtin_amdgcn_mfma_f32_16x16x32_f16(aRe[cc][kk], bRe, xr, 0, 0, 0);
            xr = __builtin_amdgcn_mfma_f32_16x16x32_f16(aMn[cc][kk], bIm, xr, 0, 0, 0);
            xi = __builtin_amdgcn_mfma_f32_16x16x32_f16(aRe[cc][kk], bIm, xi, 0, 0, 0);
            xi = __builtin_amdgcn_mfma_f32_16x16x32_f16(aIm[cc][kk], bRe, xi, 0, 0, 0);
          }
          #pragma unroll
          for (int r = 0; r < 4; ++r)
            eAcc[cc][ct][r] = fmaf(xr[r], xr[r], fmaf(xi[r], xi[r], eAcc[cc][ct][r]));
        }
      }
      if (k < 2) {
        const int nb = kb ^ 1;
        *(uint4*)&sP[nb][0][r0s][c8s] = nR0;
        *(uint4*)&sP[nb][1][r0s][c8s] = nI0;
        *(uint4*)&sP[nb][0][r1s][c8s] = nR1;
        *(uint4*)&sP[nb][1][r1s][c8s] = nI1;
      }
    }

    f16* sE = (f16*)smem;
    #pragma unroll
    for (int cc = 0; cc < 2; ++cc) {
      __syncthreads();
      #pragma unroll
      for (int ct = 0; ct < 4; ++ct)
        #pragma unroll
        for (int r = 0; r < 4; ++r)
          sE[(ct*16 + l15)*PST + w*16 + l4*4 + r] = (f16)eAcc[cc][ct][r];
      __syncthreads();
      const int cg = cgg*2 + cc;
      *(uint4*)&e16[((size_t)(bsg*64 + r0s))*1024 + cg*64 + c8s] = *(const uint4*)&sE[r0s*PST + c8s];
      *(uint4*)&e16[((size_t)(bsg*64 + r1s))*1024 + cg*64 + c8s] = *(const uint4*)&sE[r1s*PST + c8s];
    }
  }
  gbar(bar1);

  // ================= Phase C: head (all 512 blocks, 8 bt each) ==========
  {
    float* sW1 = (float*)smem;                 // 16384 B
    float (*pr)[64] = (float(*)[64])(smem + 16384);
    float (*h1)[64] = (float(*)[64])(smem + 17408);
    float (*lg)[8]  = (float(*)[8]) (smem + 18432);
    const int q = tid >> 6, j = tid & 63;
    const float lam = Lam[0], om = 1.f - lam;
    const float l2om = log2f(om);

    for (int i = tid*4; i < 4096; i += 1024)
      *(float4*)&sW1[i] = *(const float4*)&W1[i];

    #pragma unroll
    for (int ii = 0; ii < 2; ++ii) {
      const int bt = bid*8 + ii*4 + q;
      const int b = bt >> 7, t = bt & (TT-1);

      float acc = 0.f, wD = BETA_C * lam;
      const int nd = min(ND, t + 1);
      for (int D = 0; D < nd; ++D) {
        acc += wD * (float)e16[(size_t)(b*TT + t - D)*1024 + D*64 + j];
        wD *= om;
      }
      const float omt = exp2f((float)(t + 1) * l2om);
      acc += (BETA_C*omt + (1.f - BETA_C)) * kn[j] * (1.f/64.f);
      pr[q][j] = acc;
      __syncthreads();

      float a1 = b1[j];
      for (int dd = 0; dd < 64; ++dd) a1 = fmaf(pr[q][dd], sW1[dd*64 + j], a1);
      h1[q][j] = fmaxf(a1, 0.f);
      __syncthreads();

      if (j < 6) {
        float a2 = b2[j];
        for (int c = 0; c < 64; ++c) a2 = fmaf(h1[q][c], W2[c*6 + j], a2);
        lg[q][j] = tanhf(a2);
      }
      __syncthreads();
      if (j < 6) {
        float mxv = -1e30f;
        #pragma unroll
        for (int n = 0; n < 6; ++n) mxv = fmaxf(mxv, lg[q][n]);
        float se = 0.f;
        #pragma unroll
        for (int n = 0; n < 6; ++n) se += expf(lg[q][n] - mxv);
        out[bt*6 + j] = lg[q][j] - mxv - logf(se);
      }
      __syncthreads();
    }
  }
}

// ---------------------------------------------------------------------------
extern "C" void kernel_launch(void* const* d_in, const int* in_sizes, int n_in,
                              void* d_out, int out_size, void* d_ws, size_t ws_size,
                              hipStream_t stream)
{
  const float* mod0  = (const float*)d_in[0];
  const float* Wp0   = (const float*)d_in[1];
  const float* bp0   = (const float*)d_in[2];
  const float* mod1  = (const float*)d_in[3];
  const float* Wp1   = (const float*)d_in[4];
  const float* bp1   = (const float*)d_in[5];
  const float* mod2  = (const float*)d_in[6];
  const float* Wp2   = (const float*)d_in[7];
  const float* bp2   = (const float*)d_in[8];
  const float* smask = (const float*)d_in[9];
  const float* ptab  = (const float*)d_in[11];
  const float* Uhr   = (const float*)d_in[12];
  const float* Uhi   = (const float*)d_in[13];
  const float* Uxr   = (const float*)d_in[14];
  const float* Uxi   = (const float*)d_in[15];
  const float* Lam   = (const float*)d_in[16];
  const float* Kr    = (const float*)d_in[17];
  const float* Ki    = (const float*)d_in[18];
  const float* W1    = (const float*)d_in[19];
  const float* b1    = (const float*)d_in[20];
  const float* W2    = (const float*)d_in[21];
  const float* b2    = (const float*)d_in[22];

  char* ws = (char*)d_ws;
  float*    kn   = (float*)(ws);                        // 256 B
  unsigned* bar0 = (unsigned*)(ws + 4096);
  unsigned* bar1 = (unsigned*)(ws + 4224);
  f16*      Cre  = (f16*)(ws + ((size_t)1024 << 10));   // 128KB each
  f16*      Cim  = (f16*)(ws + ((size_t)1280 << 10));
  f16*      Cmn  = (f16*)(ws + ((size_t)1536 << 10));
  f16*      PsiR = (f16*)(ws + ((size_t)2 << 20));      // 512KB each
  f16*      PsiI = (f16*)(ws + ((size_t)4 << 20));
  f16*      e16  = (f16*)(ws + ((size_t)6 << 20));      // 8.4MB
  if (ws_size < ((size_t)16 << 20)) return;

  // zero the two barrier counters each call (capture-safe async memset)
  hipMemsetAsync(ws + 4096, 0, 256, stream);

  k_all<<<512, 256, 0, stream>>>(mod0, Wp0, bp0, mod1, Wp1, bp1, mod2, Wp2, bp2,
                                 smask, ptab, Uhr, Uhi, Uxr, Uxi, Kr, Ki, Lam,
                                 W1, b1, W2, b2, PsiR, PsiI, Cre, Cim, Cmn,
                                 kn, e16, bar0, bar1, (float*)d_out);
}

// Round 16
// 50.228 us; speedup vs baseline: 3.7832x; 2.5636x over previous
//
#include <hip/hip_runtime.h>
#include <hip/hip_bf16.h>
#include <math.h>

// Problem constants
#define DD 64
#define TT 128
#define BBATCH 32
#define BT (BBATCH*TT)         // 4096
#define ND 16                  // Delta truncation: (1-lam)^16 ~ 1.5e-5 for lam=0.5
#define BETA_C 0.8f
#define TWO_PI_R 6.28f         // repo uses 2*3.14
#define LG2_10000 13.28771237954945f
#define SW 328                 // f16 LDS row stride for prep staging
#define PST 72                 // E-phase psi LDS stride

typedef float2 cf;
typedef _Float16 f16;
typedef _Float16 half8 __attribute__((ext_vector_type(8)));
typedef _Float16 half4 __attribute__((ext_vector_type(4)));
typedef float f32x4 __attribute__((ext_vector_type(4)));

__device__ __forceinline__ void cfma(cf& acc, cf a, cf b){            // acc += a*b
  acc.x = fmaf(a.x, b.x, fmaf(-a.y, b.y, acc.x));
  acc.y = fmaf(a.x, b.y, fmaf( a.y, b.x, acc.y));
}

// ---------------------------------------------------------------------------
// prep GEMM phase, 8 bt-rows per block (R10 math, halved rows -> 2x grid).
// B-tile rows 8..15 are zeroed; their outputs are discarded by the caller.
// ---------------------------------------------------------------------------
template<int KDIM, int KPAD>
__device__ __forceinline__ f32x4 prep_phase8(
    const float* __restrict__ Wp, const float* __restrict__ modg,
    f16* sWpT, f16* sMod, int tid, int w, int l15, int l4)
{
  __syncthreads();
  constexpr int PAD = KPAD - KDIM;
  for (int i = tid; i < 64*PAD; i += 256) {
    const int r = i / PAD, p = KDIM + (i - r*PAD);
    sWpT[r*SW + p] = (f16)0.f;
  }
  // zero the whole 16-row mod tile (rows 8..15 stay zero)
  for (int i = tid*8; i < 16*SW; i += 2048)
    *(uint4*)&sMod[i] = (uint4){0u,0u,0u,0u};
  __syncthreads();   // zeros visible before partial fill
  for (int i = tid; i < KDIM*16; i += 256) {
    const int p = i >> 4, c4 = (i & 15) << 2;
    const float4 v = *(const float4*)&Wp[p*64 + c4];
    sWpT[(c4+0)*SW + p] = (f16)v.x;
    sWpT[(c4+1)*SW + p] = (f16)v.y;
    sWpT[(c4+2)*SW + p] = (f16)v.z;
    sWpT[(c4+3)*SW + p] = (f16)v.w;
  }
  for (int i = tid; i < (8*KDIM)/4; i += 256) {
    const float4 v = *(const float4*)&modg[i*4];
    const float vv[4] = {v.x, v.y, v.z, v.w};
    #pragma unroll
    for (int e2 = 0; e2 < 4; ++e2) {
      const int flat = i*4 + e2;
      const int r = flat / KDIM, p = flat - r*KDIM;
      sMod[r*SW + p] = (f16)vv[e2];
    }
  }
  __syncthreads();
  f32x4 acc = {0.f, 0.f, 0.f, 0.f};
  #pragma unroll
  for (int s = 0; s < KPAD/32; ++s) {
    const half8 a = *(const half8*)&sWpT[(w*16 + l15)*SW + s*32 + l4*8];
    const half8 b = *(const half8*)&sMod[l15*SW + s*32 + l4*8];
    acc = __builtin_amdgcn_mfma_f32_16x16x32_f16(a, b, acc, 0, 0, 0);
  }
  return acc;
}

// ---------------------------------------------------------------------------
// Kernel 1 (front): blocks [0,64) = TC power-chain (register U rows, 4-wave
// p-split); blocks [64,576) = MFMA prep, 8 bt-rows per block (grid 2x R12's:
// 576 blocks ~ 2.25/CU so prep's L2 staging latency overlaps across blocks).
// ---------------------------------------------------------------------------
__global__ __launch_bounds__(256) void k_front(
    const float* __restrict__ mod0, const float* __restrict__ Wp0, const float* __restrict__ bp0,
    const float* __restrict__ mod1, const float* __restrict__ Wp1, const float* __restrict__ bp1,
    const float* __restrict__ mod2, const float* __restrict__ Wp2, const float* __restrict__ bp2,
    const float* __restrict__ smask, const float* __restrict__ ptab,
    const float* __restrict__ Uhr, const float* __restrict__ Uhi,
    const float* __restrict__ Uxr, const float* __restrict__ Uxi,
    const float* __restrict__ Kr,  const float* __restrict__ Ki,
    f16* __restrict__ PsiR, f16* __restrict__ PsiI,
    f16* __restrict__ Cre, f16* __restrict__ Cim, f16* __restrict__ Cmn,
    float* __restrict__ kn)
{
  __shared__ __align__(16) char smem[59136];
  const int tid = threadIdx.x, w = tid >> 6, lane = tid & 63;
  const int l15 = lane & 15, l4 = lane >> 4;

  if (blockIdx.x < 64) {
    cf* st = (cf*)smem;                         // [64]
    cf (*red)[64] = (cf(*)[64])(smem + 512);    // [8][64]
    const int j = blockIdx.x, c = lane;

    cf uh[16], ux[16];
    #pragma unroll
    for (int i = 0; i < 16; ++i) {
      const int p = w*16 + i;
      uh[i] = make_float2(Uhr[p*64 + c], Uhi[p*64 + c]);
      ux[i] = make_float2(Uxr[p*64 + c], Uxi[p*64 + c]);
    }
    if (w == 0) {
      const cf kj = make_float2(Kr[j*64 + c], -Ki[j*64 + c]);
      st[c] = kj;
      float q = fmaf(kj.x, kj.x, kj.y*kj.y);
      #pragma unroll
      for (int off = 32; off; off >>= 1) q += __shfl_xor(q, off);
      if (c == 0) kn[j] = q;
    }
    __syncthreads();

    for (int D = 0; D < ND; ++D) {
      cf cA = {0.f,0.f}, cB = {0.f,0.f}, tA = {0.f,0.f}, tB = {0.f,0.f};
      #pragma unroll
      for (int i = 0; i < 16; i += 2) {
        const cf t0 = st[w*16 + i], t1 = st[w*16 + i + 1];
        cfma(cA, t0, ux[i]); cfma(cB, t1, ux[i+1]);
        cfma(tA, t0, uh[i]); cfma(tB, t1, uh[i+1]);
      }
      red[w][c]     = make_float2(cA.x + cB.x, cA.y + cB.y);
      red[4 + w][c] = make_float2(tA.x + tB.x, tA.y + tB.y);
      __syncthreads();
      if (w == 0) {
        const cf r0 = red[0][c], r1 = red[1][c], r2 = red[2][c], r3 = red[3][c];
        const float crx = r0.x + r1.x + r2.x + r3.x;
        const float cry = r0.y + r1.y + r2.y + r3.y;
        const size_t row = (size_t)(D*64 + j)*64 + c;
        Cre[row] = (f16)crx;
        Cim[row] = (f16)cry;
        Cmn[row] = (f16)(-cry);
      } else if (w == 1) {
        const cf r0 = red[4][c], r1 = red[5][c], r2 = red[6][c], r3 = red[7][c];
        st[c] = make_float2(r0.x + r1.x + r2.x + r3.x, r0.y + r1.y + r2.y + r3.y);
      }
      __syncthreads();
    }
    return;
  }

  // ---------------- prep: 8 bt rows via 3 MFMA GEMM phases ----------------
  f16* sWpT = (f16*)smem;                        // [64][SW]  41,984 B
  f16* sMod = (f16*)(smem + 41984);              // [16][SW]  10,496 B
  float* repS = (float*)(smem + 52480);          // [3][8][68] 6,528 B
  const int bt0 = (int)(blockIdx.x - 64) * 8;

  const f32x4 a0 = prep_phase8<300,320>(Wp0, mod0 + (size_t)bt0*300, sWpT, sMod, tid, w, l15, l4);
  if (l15 < 8) {
    #pragma unroll
    for (int r = 0; r < 4; ++r) {
      const int d = w*16 + l4*4 + r;
      repS[(0*8 + l15)*68 + d] = a0[r] + bp0[d];
    }
  }
  const f32x4 a1 = prep_phase8<74,96>(Wp1, mod1 + (size_t)bt0*74, sWpT, sMod, tid, w, l15, l4);
  if (l15 < 8) {
    #pragma unroll
    for (int r = 0; r < 4; ++r) {
      const int d = w*16 + l4*4 + r;
      repS[(1*8 + l15)*68 + d] = a1[r] + bp1[d];
    }
  }
  const f32x4 a2 = prep_phase8<35,64>(Wp2, mod2 + (size_t)bt0*35, sWpT, sMod, tid, w, l15, l4);
  if (l15 < 8) {
    #pragma unroll
    for (int r = 0; r < 4; ++r) {
      const int d = w*16 + l4*4 + r;
      repS[(2*8 + l15)*68 + d] = a2[r] + bp2[d];
    }
  }
  __syncthreads();

  // epilogue: threads 0..127, thread (btl = tid>>4 in 0..7, g = tid&15)
  const int btl = tid >> 4, g = tid & 15;
  if (btl < 8) {
    float4 v0 = *(float4*)&repS[(0*8 + btl)*68 + g*4];
    float4 v1 = *(float4*)&repS[(1*8 + btl)*68 + g*4];
    float4 v2 = *(float4*)&repS[(2*8 + btl)*68 + g*4];
    v0.x = fmaxf(v0.x, 0.f); v0.y = fmaxf(v0.y, 0.f); v0.z = fmaxf(v0.z, 0.f); v0.w = fmaxf(v0.w, 0.f);
    v1.x = fmaxf(v1.x, 0.f); v1.y = fmaxf(v1.y, 0.f); v1.z = fmaxf(v1.z, 0.f); v1.w = fmaxf(v1.w, 0.f);
    v2.x = fmaxf(v2.x, 0.f); v2.y = fmaxf(v2.y, 0.f); v2.z = fmaxf(v2.z, 0.f); v2.w = fmaxf(v2.w, 0.f);

    float q0 = v0.x*v0.x + v0.y*v0.y + v0.z*v0.z + v0.w*v0.w;
    float q1 = v1.x*v1.x + v1.y*v1.y + v1.z*v1.z + v1.w*v1.w;
    float q2 = v2.x*v2.x + v2.y*v2.y + v2.z*v2.z + v2.w*v2.w;
    #pragma unroll
    for (int off = 8; off; off >>= 1) {      // reduce over the 16 g-lanes
      q0 += __shfl_xor(q0, off);
      q1 += __shfl_xor(q1, off);
      q2 += __shfl_xor(q2, off);
    }
    const float n0 = sqrtf(q0), n1 = sqrtf(q1), n2 = sqrtf(q2);
    const float mx = fmaxf(n0, fmaxf(n1, n2));
    const float e0 = expf(n0 - mx), e1 = expf(n1 - mx), e2 = expf(n2 - mx);
    const float inv = 1.f / (e0 + e1 + e2);
    const float sc0 = sqrtf(e0*inv) / fmaxf(n0, 1e-12f);
    const float sc1 = sqrtf(e1*inv) / fmaxf(n1, 1e-12f);
    const float sc2 = sqrtf(e2*inv) / fmaxf(n2, 1e-12f);

    const int btg = bt0 + btl;
    const int t = btg & (TT-1);
    const int sid = (smask[btg*2 + 1] > smask[btg*2]) ? 1 : 0;

    float cs[4], sn[4];
    #pragma unroll
    for (int i = 0; i < 4; ++i) {
      const int d = g*4 + i;
      const float freq = exp2f(-((float)d * (1.f/64.f)) * LG2_10000);
      const float ph = (float)t * freq + ptab[sid*64 + d] * TWO_PI_R;
      sincosf(ph, &sn[i], &cs[i]);
    }
    const float am0[4] = {v0.x*sc0, v0.y*sc0, v0.z*sc0, v0.w*sc0};
    const float am1[4] = {v1.x*sc1, v1.y*sc1, v1.z*sc1, v1.w*sc1};
    const float am2[4] = {v2.x*sc2, v2.y*sc2, v2.z*sc2, v2.w*sc2};
    half4 wr, wi;
    #pragma unroll
    for (int i = 0; i < 4; ++i) { wr[i] = (f16)(am0[i]*cs[i]); wi[i] = (f16)(am0[i]*sn[i]); }
    *(half4*)&PsiR[(size_t)(0*BT + btg)*64 + g*4] = wr;
    *(half4*)&PsiI[(size_t)(0*BT + btg)*64 + g*4] = wi;
    #pragma unroll
    for (int i = 0; i < 4; ++i) { wr[i] = (f16)(am1[i]*cs[i]); wi[i] = (f16)(am1[i]*sn[i]); }
    *(half4*)&PsiR[(size_t)(1*BT + btg)*64 + g*4] = wr;
    *(half4*)&PsiI[(size_t)(1*BT + btg)*64 + g*4] = wi;
    #pragma unroll
    for (int i = 0; i < 4; ++i) { wr[i] = (f16)(am2[i]*cs[i]); wi[i] = (f16)(am2[i]*sn[i]); }
    *(half4*)&PsiR[(size_t)(2*BT + btg)*64 + g*4] = wr;
    *(half4*)&PsiI[(size_t)(2*BT + btg)*64 + g*4] = wi;
  }
}

// ---------------------------------------------------------------------------
// Kernel 2 (MFMA): e16[bs][Dj] = sum_k |alpha|^2. R12 body verbatim (proven):
// k-dbuf psi staging (36.9 KB LDS), hoisted A-frags, reg prefetch, coalesced
// e-writes via LDS transpose. Grid 512 = 64 bsg x 8 cgg (2 cg each).
// ---------------------------------------------------------------------------
__global__ __launch_bounds__(256) void k_E(
    const f16* __restrict__ Cre, const f16* __restrict__ Cim, const f16* __restrict__ Cmn,
    const f16* __restrict__ PsiR, const f16* __restrict__ PsiI,
    f16* __restrict__ e16)
{
  __shared__ __align__(16) f16 sP[2][2][64][PST];   // 36,864 B
  const int bsg = blockIdx.x >> 3, cgg = blockIdx.x & 7;
  const int tid = threadIdx.x, w = tid >> 6, lane = tid & 63;
  const int l15 = lane & 15, l4 = lane >> 4;

  half8 aRe[2][2], aIm[2][2], aMn[2][2];
  #pragma unroll
  for (int cc = 0; cc < 2; ++cc) {
    const size_t arow = ((size_t)((cgg*2 + cc)*64 + w*16 + l15))*64 + l4*8;
    aRe[cc][0] = *(const half8*)&Cre[arow]; aRe[cc][1] = *(const half8*)&Cre[arow + 32];
    aIm[cc][0] = *(const half8*)&Cim[arow]; aIm[cc][1] = *(const half8*)&Cim[arow + 32];
    aMn[cc][0] = *(const half8*)&Cmn[arow]; aMn[cc][1] = *(const half8*)&Cmn[arow + 32];
  }

  const int r0s = tid >> 3, c8s = (tid & 7) << 3;
  const int r1s = (tid + 256) >> 3;
  {
    const size_t g0 = ((size_t)(0*BT + bsg*64 + r0s))*64 + c8s;
    const size_t g1 = ((size_t)(0*BT + bsg*64 + r1s))*64 + c8s;
    *(uint4*)&sP[0][0][r0s][c8s] = *(const uint4*)&PsiR[g0];
    *(uint4*)&sP[0][1][r0s][c8s] = *(const uint4*)&PsiI[g0];
    *(uint4*)&sP[0][0][r1s][c8s] = *(const uint4*)&PsiR[g1];
    *(uint4*)&sP[0][1][r1s][c8s] = *(const uint4*)&PsiI[g1];
  }

  f32x4 eAcc[2][4];
  #pragma unroll
  for (int cc = 0; cc < 2; ++cc)
    #pragma unroll
    for (int ct = 0; ct < 4; ++ct) eAcc[cc][ct] = (f32x4){0.f,0.f,0.f,0.f};

  #pragma unroll
  for (int k = 0; k < 3; ++k) {
    uint4 nR0, nI0, nR1, nI1;
    if (k < 2) {
      const size_t g0 = ((size_t)((k+1)*BT + bsg*64 + r0s))*64 + c8s;
      const size_t g1 = ((size_t)((k+1)*BT + bsg*64 + r1s))*64 + c8s;
      nR0 = *(const uint4*)&PsiR[g0];
      nI0 = *(const uint4*)&PsiI[g0];
      nR1 = *(const uint4*)&PsiR[g1];
      nI1 = *(const uint4*)&PsiI[g1];
    }
    __syncthreads();
    const int kb = k & 1;
    #pragma unroll
    for (int cc = 0; cc < 2; ++cc) {
      #pragma unroll
      for (int ct = 0; ct < 4; ++ct) {
        f32x4 xr = {0.f,0.f,0.f,0.f}, xi = {0.f,0.f,0.f,0.f};
        #pragma unroll
        for (int kk = 0; kk < 2; ++kk) {
          const half8 bRe = *(const half8*)&sP[kb][0][ct*16 + l15][l4*8 + kk*32];
          const half8 bIm = *(const half8*)&sP[kb][1][ct*16 + l15][l4*8 + kk*32];
          xr = __builtin_amdgcn_mfma_f32_16x16x32_f16(aRe[cc][kk], bRe, xr, 0, 0, 0);
          xr = __builtin_amdgcn_mfma_f32_16x16x32_f16(aMn[cc][kk], bIm, xr, 0, 0, 0);
          xi = __builtin_amdgcn_mfma_f32_16x16x32_f16(aRe[cc][kk], bIm, xi, 0, 0, 0);
          xi = __builtin_amdgcn_mfma_f32_16x16x32_f16(aIm[cc][kk], bRe, xi, 0, 0, 0);
        }
        #pragma unroll
        for (int r = 0; r < 4; ++r)
          eAcc[cc][ct][r] = fmaf(xr[r], xr[r], fmaf(xi[r], xi[r], eAcc[cc][ct][r]));
      }
    }
    if (k < 2) {
      const int nb = kb ^ 1;
      *(uint4*)&sP[nb][0][r0s][c8s] = nR0;
      *(uint4*)&sP[nb][1][r0s][c8s] = nI0;
      *(uint4*)&sP[nb][0][r1s][c8s] = nR1;
      *(uint4*)&sP[nb][1][r1s][c8s] = nI1;
    }
  }

  f16* sE = (f16*)sP;
  #pragma unroll
  for (int cc = 0; cc < 2; ++cc) {
    __syncthreads();
    #pragma unroll
    for (int ct = 0; ct < 4; ++ct)
      #pragma unroll
      for (int r = 0; r < 4; ++r)
        sE[(ct*16 + l15)*PST + w*16 + l4*4 + r] = (f16)eAcc[cc][ct][r];
    __syncthreads();
    const int cg = cgg*2 + cc;
    *(uint4*)&e16[((size_t)(bsg*64 + r0s))*1024 + cg*64 + c8s] = *(const uint4*)&sE[r0s*PST + c8s];
    *(uint4*)&e16[((size_t)(bsg*64 + r1s))*1024 + cg*64 + c8s] = *(const uint4*)&sE[r1s*PST + c8s];
  }
}

// ---------------------------------------------------------------------------
// Kernel 3: Delta-convolution (f16 e) + identity + MLP head + log_softmax.
// W1 staged in LDS; W2 parallelized over 48 lanes (8-lane partials + shuffle
// reduce) instead of 6 serial lanes.
// ---------------------------------------------------------------------------
__global__ __launch_bounds__(256) void k_head(const f16* __restrict__ e16,
    const float* __restrict__ kn, const float* __restrict__ Lam,
    const float* __restrict__ W1, const float* __restrict__ b1,
    const float* __restrict__ W2, const float* __restrict__ b2,
    float* __restrict__ out)
{
  __shared__ float sW1[4096];     // 16 KB
  __shared__ float pr[4][64];
  __shared__ float h1[4][64];
  __shared__ float lg[4][6];
  const int tid = threadIdx.x;
  const int q = tid >> 6, j = tid & 63;
  const int bt = blockIdx.x*4 + q;
  const int b = bt >> 7, t = bt & (TT-1);
  const float lam = Lam[0], om = 1.f - lam;

  for (int i = tid*4; i < 4096; i += 1024)
    *(float4*)&sW1[i] = *(const float4*)&W1[i];

  float acc = 0.f, wD = BETA_C * lam;
  const int nd = min(ND, t + 1);
  for (int D = 0; D < nd; ++D) {
    acc += wD * (float)e16[(size_t)(b*TT + t - D)*1024 + D*64 + j];
    wD *= om;
  }
  const float omt = exp2f((float)(t + 1) * log2f(om));
  acc += (BETA_C*omt + (1.f - BETA_C)) * kn[j] * (1.f/64.f);
  pr[q][j] = acc;
  __syncthreads();

  float a1 = b1[j];
  for (int dd = 0; dd < 64; ++dd) a1 = fmaf(pr[q][dd], sW1[dd*64 + j], a1);
  h1[q][j] = fmaxf(a1, 0.f);
  __syncthreads();

  if (j < 48) {                       // class c = j>>3, 8-elem partial e = j&7
    const int c = j >> 3, e = j & 7;
    float a2 = 0.f;
    #pragma unroll
    for (int u = 0; u < 8; ++u)
      a2 = fmaf(h1[q][e*8 + u], W2[(e*8 + u)*6 + c], a2);
    a2 += __shfl_xor(a2, 1);
    a2 += __shfl_xor(a2, 2);
    a2 += __shfl_xor(a2, 4);
    if (e == 0) lg[q][c] = tanhf(a2 + b2[c]);
  }
  __syncthreads();
  if (j < 6) {
    float mx = -1e30f;
    #pragma unroll
    for (int n = 0; n < 6; ++n) mx = fmaxf(mx, lg[q][n]);
    float se = 0.f;
    #pragma unroll
    for (int n = 0; n < 6; ++n) se += expf(lg[q][n] - mx);
    out[bt*6 + j] = lg[q][j] - mx - logf(se);
  }
}

// ---------------------------------------------------------------------------
extern "C" void kernel_launch(void* const* d_in, const int* in_sizes, int n_in,
                              void* d_out, int out_size, void* d_ws, size_t ws_size,
                              hipStream_t stream)
{
  const float* mod0  = (const float*)d_in[0];
  const float* Wp0   = (const float*)d_in[1];
  const float* bp0   = (const float*)d_in[2];
  const float* mod1  = (const float*)d_in[3];
  const float* Wp1   = (const float*)d_in[4];
  const float* bp1   = (const float*)d_in[5];
  const float* mod2  = (const float*)d_in[6];
  const float* Wp2   = (const float*)d_in[7];
  const float* bp2   = (const float*)d_in[8];
  const float* smask = (const float*)d_in[9];
  const float* ptab  = (const float*)d_in[11];
  const float* Uhr   = (const float*)d_in[12];
  const float* Uhi   = (const float*)d_in[13];
  const float* Uxr   = (const float*)d_in[14];
  const float* Uxi   = (const float*)d_in[15];
  const float* Lam   = (const float*)d_in[16];
  const float* Kr    = (const float*)d_in[17];
  const float* Ki    = (const float*)d_in[18];
  const float* W1    = (const float*)d_in[19];
  const float* b1    = (const float*)d_in[20];
  const float* W2    = (const float*)d_in[21];
  const float* b2    = (const float*)d_in[22];

  char* ws = (char*)d_ws;
  float* kn   = (float*)(ws);
  f16*   Cre  = (f16*)  (ws + ((size_t)1024 << 10));  // 128KB each
  f16*   Cim  = (f16*)  (ws + ((size_t)1280 << 10));
  f16*   Cmn  = (f16*)  (ws + ((size_t)1536 << 10));
  f16*   PsiR = (f16*)  (ws + ((size_t)2 << 20));     // 512KB each
  f16*   PsiI = (f16*)  (ws + ((size_t)4 << 20));
  f16*   e16  = (f16*)  (ws + ((size_t)6 << 20));     // 8.4MB
  if (ws_size < ((size_t)16 << 20)) return;

  k_front<<<576, 256, 0, stream>>>(mod0, Wp0, bp0, mod1, Wp1, bp1, mod2, Wp2, bp2,
                                   smask, ptab, Uhr, Uhi, Uxr, Uxi, Kr, Ki,
                                   PsiR, PsiI, Cre, Cim, Cmn, kn);
  k_E<<<512, 256, 0, stream>>>(Cre, Cim, Cmn, PsiR, PsiI, e16);
  k_head<<<1024, 256, 0, stream>>>(e16, kn, Lam, W1, b1, W2, b2, (float*)d_out);
}

// Round 17
// 44.485 us; speedup vs baseline: 4.2717x; 1.1291x over previous
//
#include <hip/hip_runtime.h>
#include <hip/hip_bf16.h>
#include <math.h>

// Problem constants
#define DD 64
#define TT 128
#define BBATCH 32
#define BT (BBATCH*TT)         // 4096
#define ND 16                  // Delta truncation: (1-lam)^16 ~ 1.5e-5 for lam=0.5
#define BETA_C 0.8f
#define TWO_PI_R 6.28f         // repo uses 2*3.14
#define LG2_10000 13.28771237954945f
#define SW 328                 // f16 LDS row stride for prep staging
#define PST 72                 // E-phase psi LDS stride

typedef float2 cf;
typedef _Float16 f16;
typedef _Float16 half8 __attribute__((ext_vector_type(8)));
typedef _Float16 half4 __attribute__((ext_vector_type(4)));
typedef float f32x4 __attribute__((ext_vector_type(4)));

__device__ __forceinline__ void cfma(cf& acc, cf a, cf b){            // acc += a*b
  acc.x = fmaf(a.x, b.x, fmaf(-a.y, b.y, acc.x));
  acc.y = fmaf(a.x, b.y, fmaf( a.y, b.x, acc.y));
}

// ---------------------------------------------------------------------------
// prep GEMM phase (R10/R12 proven): 16 bt rows per block.
// ---------------------------------------------------------------------------
template<int KDIM, int KPAD>
__device__ __forceinline__ f32x4 prep_phase(
    const float* __restrict__ Wp, const float* __restrict__ modg,
    f16* sWpT, f16* sMod, int tid, int w, int l15, int l4)
{
  __syncthreads();
  constexpr int PAD = KPAD - KDIM;
  for (int i = tid; i < 64*PAD; i += 256) {
    const int r = i / PAD, p = KDIM + (i - r*PAD);
    sWpT[r*SW + p] = (f16)0.f;
  }
  for (int i = tid; i < 16*PAD; i += 256) {
    const int r = i / PAD, p = KDIM + (i - r*PAD);
    sMod[r*SW + p] = (f16)0.f;
  }
  for (int i = tid; i < KDIM*16; i += 256) {
    const int p = i >> 4, c4 = (i & 15) << 2;
    const float4 v = *(const float4*)&Wp[p*64 + c4];
    sWpT[(c4+0)*SW + p] = (f16)v.x;
    sWpT[(c4+1)*SW + p] = (f16)v.y;
    sWpT[(c4+2)*SW + p] = (f16)v.z;
    sWpT[(c4+3)*SW + p] = (f16)v.w;
  }
  for (int i = tid; i < (16*KDIM)/4; i += 256) {
    const float4 v = *(const float4*)&modg[i*4];
    const float vv[4] = {v.x, v.y, v.z, v.w};
    #pragma unroll
    for (int e2 = 0; e2 < 4; ++e2) {
      const int flat = i*4 + e2;
      const int r = flat / KDIM, p = flat - r*KDIM;
      sMod[r*SW + p] = (f16)vv[e2];
    }
  }
  __syncthreads();
  f32x4 acc = {0.f, 0.f, 0.f, 0.f};
  #pragma unroll
  for (int s = 0; s < KPAD/32; ++s) {
    const half8 a = *(const half8*)&sWpT[(w*16 + l15)*SW + s*32 + l4*8];
    const half8 b = *(const half8*)&sMod[l15*SW + s*32 + l4*8];
    acc = __builtin_amdgcn_mfma_f32_16x16x32_f16(a, b, acc, 0, 0, 0);
  }
  return acc;
}

// ---------------------------------------------------------------------------
// Kernel 1 (front): blocks [0,64) = TC power-chain; [64,320) = MFMA prep
// (16 bt-rows per block). R12 verbatim (best verified config, 46.16us).
// ---------------------------------------------------------------------------
__global__ __launch_bounds__(256) void k_front(
    const float* __restrict__ mod0, const float* __restrict__ Wp0, const float* __restrict__ bp0,
    const float* __restrict__ mod1, const float* __restrict__ Wp1, const float* __restrict__ bp1,
    const float* __restrict__ mod2, const float* __restrict__ Wp2, const float* __restrict__ bp2,
    const float* __restrict__ smask, const float* __restrict__ ptab,
    const float* __restrict__ Uhr, const float* __restrict__ Uhi,
    const float* __restrict__ Uxr, const float* __restrict__ Uxi,
    const float* __restrict__ Kr,  const float* __restrict__ Ki,
    f16* __restrict__ PsiR, f16* __restrict__ PsiI,
    f16* __restrict__ Cre, f16* __restrict__ Cim, f16* __restrict__ Cmn,
    float* __restrict__ kn)
{
  __shared__ __align__(16) char smem[65536];
  const int tid = threadIdx.x, w = tid >> 6, lane = tid & 63;
  const int l15 = lane & 15, l4 = lane >> 4;

  if (blockIdx.x < 64) {
    cf* st = (cf*)smem;                         // [64]
    cf (*red)[64] = (cf(*)[64])(smem + 512);    // [8][64]
    const int j = blockIdx.x, c = lane;

    cf uh[16], ux[16];
    #pragma unroll
    for (int i = 0; i < 16; ++i) {
      const int p = w*16 + i;
      uh[i] = make_float2(Uhr[p*64 + c], Uhi[p*64 + c]);
      ux[i] = make_float2(Uxr[p*64 + c], Uxi[p*64 + c]);
    }
    if (w == 0) {
      const cf kj = make_float2(Kr[j*64 + c], -Ki[j*64 + c]);
      st[c] = kj;
      float q = fmaf(kj.x, kj.x, kj.y*kj.y);
      #pragma unroll
      for (int off = 32; off; off >>= 1) q += __shfl_xor(q, off);
      if (c == 0) kn[j] = q;
    }
    __syncthreads();

    for (int D = 0; D < ND; ++D) {
      cf cA = {0.f,0.f}, cB = {0.f,0.f}, tA = {0.f,0.f}, tB = {0.f,0.f};
      #pragma unroll
      for (int i = 0; i < 16; i += 2) {
        const cf t0 = st[w*16 + i], t1 = st[w*16 + i + 1];
        cfma(cA, t0, ux[i]); cfma(cB, t1, ux[i+1]);
        cfma(tA, t0, uh[i]); cfma(tB, t1, uh[i+1]);
      }
      red[w][c]     = make_float2(cA.x + cB.x, cA.y + cB.y);
      red[4 + w][c] = make_float2(tA.x + tB.x, tA.y + tB.y);
      __syncthreads();
      if (w == 0) {
        const cf r0 = red[0][c], r1 = red[1][c], r2 = red[2][c], r3 = red[3][c];
        const float crx = r0.x + r1.x + r2.x + r3.x;
        const float cry = r0.y + r1.y + r2.y + r3.y;
        const size_t row = (size_t)(D*64 + j)*64 + c;
        Cre[row] = (f16)crx;
        Cim[row] = (f16)cry;
        Cmn[row] = (f16)(-cry);
      } else if (w == 1) {
        const cf r0 = red[4][c], r1 = red[5][c], r2 = red[6][c], r3 = red[7][c];
        st[c] = make_float2(r0.x + r1.x + r2.x + r3.x, r0.y + r1.y + r2.y + r3.y);
      }
      __syncthreads();
    }
    return;
  }

  // ---------------- prep: 16 bt rows via 3 MFMA GEMM phases ----------------
  f16* sWpT = (f16*)smem;                        // [64][SW]
  f16* sMod = (f16*)(smem + 41984);              // [16][SW]
  float* repS = (float*)(smem + 52480);          // [3][16][68]
  const int bt0 = (int)(blockIdx.x - 64) * 16;

  const f32x4 a0 = prep_phase<300,320>(Wp0, mod0 + (size_t)bt0*300, sWpT, sMod, tid, w, l15, l4);
  #pragma unroll
  for (int r = 0; r < 4; ++r) {
    const int d = w*16 + l4*4 + r;
    repS[(0*16 + l15)*68 + d] = a0[r] + bp0[d];
  }
  const f32x4 a1 = prep_phase<74,96>(Wp1, mod1 + (size_t)bt0*74, sWpT, sMod, tid, w, l15, l4);
  #pragma unroll
  for (int r = 0; r < 4; ++r) {
    const int d = w*16 + l4*4 + r;
    repS[(1*16 + l15)*68 + d] = a1[r] + bp1[d];
  }
  const f32x4 a2 = prep_phase<35,64>(Wp2, mod2 + (size_t)bt0*35, sWpT, sMod, tid, w, l15, l4);
  #pragma unroll
  for (int r = 0; r < 4; ++r) {
    const int d = w*16 + l4*4 + r;
    repS[(2*16 + l15)*68 + d] = a2[r] + bp2[d];
  }
  __syncthreads();

  const int btl = tid >> 4, g = tid & 15;
  float4 v0 = *(float4*)&repS[(0*16 + btl)*68 + g*4];
  float4 v1 = *(float4*)&repS[(1*16 + btl)*68 + g*4];
  float4 v2 = *(float4*)&repS[(2*16 + btl)*68 + g*4];
  v0.x = fmaxf(v0.x, 0.f); v0.y = fmaxf(v0.y, 0.f); v0.z = fmaxf(v0.z, 0.f); v0.w = fmaxf(v0.w, 0.f);
  v1.x = fmaxf(v1.x, 0.f); v1.y = fmaxf(v1.y, 0.f); v1.z = fmaxf(v1.z, 0.f); v1.w = fmaxf(v1.w, 0.f);
  v2.x = fmaxf(v2.x, 0.f); v2.y = fmaxf(v2.y, 0.f); v2.z = fmaxf(v2.z, 0.f); v2.w = fmaxf(v2.w, 0.f);

  float q0 = v0.x*v0.x + v0.y*v0.y + v0.z*v0.z + v0.w*v0.w;
  float q1 = v1.x*v1.x + v1.y*v1.y + v1.z*v1.z + v1.w*v1.w;
  float q2 = v2.x*v2.x + v2.y*v2.y + v2.z*v2.z + v2.w*v2.w;
  #pragma unroll
  for (int off = 8; off; off >>= 1) {
    q0 += __shfl_xor(q0, off);
    q1 += __shfl_xor(q1, off);
    q2 += __shfl_xor(q2, off);
  }
  const float n0 = sqrtf(q0), n1 = sqrtf(q1), n2 = sqrtf(q2);
  const float mx = fmaxf(n0, fmaxf(n1, n2));
  const float e0 = expf(n0 - mx), e1 = expf(n1 - mx), e2 = expf(n2 - mx);
  const float inv = 1.f / (e0 + e1 + e2);
  const float sc0 = sqrtf(e0*inv) / fmaxf(n0, 1e-12f);
  const float sc1 = sqrtf(e1*inv) / fmaxf(n1, 1e-12f);
  const float sc2 = sqrtf(e2*inv) / fmaxf(n2, 1e-12f);

  const int btg = bt0 + btl;
  const int t = btg & (TT-1);
  const int sid = (smask[btg*2 + 1] > smask[btg*2]) ? 1 : 0;

  float cs[4], sn[4];
  #pragma unroll
  for (int i = 0; i < 4; ++i) {
    const int d = g*4 + i;
    const float freq = exp2f(-((float)d * (1.f/64.f)) * LG2_10000);
    const float ph = (float)t * freq + ptab[sid*64 + d] * TWO_PI_R;
    sincosf(ph, &sn[i], &cs[i]);
  }
  const float am0[4] = {v0.x*sc0, v0.y*sc0, v0.z*sc0, v0.w*sc0};
  const float am1[4] = {v1.x*sc1, v1.y*sc1, v1.z*sc1, v1.w*sc1};
  const float am2[4] = {v2.x*sc2, v2.y*sc2, v2.z*sc2, v2.w*sc2};
  half4 wr, wi;
  #pragma unroll
  for (int i = 0; i < 4; ++i) { wr[i] = (f16)(am0[i]*cs[i]); wi[i] = (f16)(am0[i]*sn[i]); }
  *(half4*)&PsiR[(size_t)(0*BT + btg)*64 + g*4] = wr;
  *(half4*)&PsiI[(size_t)(0*BT + btg)*64 + g*4] = wi;
  #pragma unroll
  for (int i = 0; i < 4; ++i) { wr[i] = (f16)(am1[i]*cs[i]); wi[i] = (f16)(am1[i]*sn[i]); }
  *(half4*)&PsiR[(size_t)(1*BT + btg)*64 + g*4] = wr;
  *(half4*)&PsiI[(size_t)(1*BT + btg)*64 + g*4] = wi;
  #pragma unroll
  for (int i = 0; i < 4; ++i) { wr[i] = (f16)(am2[i]*cs[i]); wi[i] = (f16)(am2[i]*sn[i]); }
  *(half4*)&PsiR[(size_t)(2*BT + btg)*64 + g*4] = wr;
  *(half4*)&PsiI[(size_t)(2*BT + btg)*64 + g*4] = wi;
}

// ---------------------------------------------------------------------------
// Kernel 2 (MFMA): e16[bs][Dj] = sum_k |alpha|^2. R12 verbatim (proven).
// ---------------------------------------------------------------------------
__global__ __launch_bounds__(256) void k_E(
    const f16* __restrict__ Cre, const f16* __restrict__ Cim, const f16* __restrict__ Cmn,
    const f16* __restrict__ PsiR, const f16* __restrict__ PsiI,
    f16* __restrict__ e16)
{
  __shared__ __align__(16) f16 sP[2][2][64][PST];   // 36,864 B
  const int bsg = blockIdx.x >> 3, cgg = blockIdx.x & 7;
  const int tid = threadIdx.x, w = tid >> 6, lane = tid & 63;
  const int l15 = lane & 15, l4 = lane >> 4;

  half8 aRe[2][2], aIm[2][2], aMn[2][2];
  #pragma unroll
  for (int cc = 0; cc < 2; ++cc) {
    const size_t arow = ((size_t)((cgg*2 + cc)*64 + w*16 + l15))*64 + l4*8;
    aRe[cc][0] = *(const half8*)&Cre[arow]; aRe[cc][1] = *(const half8*)&Cre[arow + 32];
    aIm[cc][0] = *(const half8*)&Cim[arow]; aIm[cc][1] = *(const half8*)&Cim[arow + 32];
    aMn[cc][0] = *(const half8*)&Cmn[arow]; aMn[cc][1] = *(const half8*)&Cmn[arow + 32];
  }

  const int r0s = tid >> 3, c8s = (tid & 7) << 3;
  const int r1s = (tid + 256) >> 3;
  {
    const size_t g0 = ((size_t)(0*BT + bsg*64 + r0s))*64 + c8s;
    const size_t g1 = ((size_t)(0*BT + bsg*64 + r1s))*64 + c8s;
    *(uint4*)&sP[0][0][r0s][c8s] = *(const uint4*)&PsiR[g0];
    *(uint4*)&sP[0][1][r0s][c8s] = *(const uint4*)&PsiI[g0];
    *(uint4*)&sP[0][0][r1s][c8s] = *(const uint4*)&PsiR[g1];
    *(uint4*)&sP[0][1][r1s][c8s] = *(const uint4*)&PsiI[g1];
  }

  f32x4 eAcc[2][4];
  #pragma unroll
  for (int cc = 0; cc < 2; ++cc)
    #pragma unroll
    for (int ct = 0; ct < 4; ++ct) eAcc[cc][ct] = (f32x4){0.f,0.f,0.f,0.f};

  #pragma unroll
  for (int k = 0; k < 3; ++k) {
    uint4 nR0, nI0, nR1, nI1;
    if (k < 2) {
      const size_t g0 = ((size_t)((k+1)*BT + bsg*64 + r0s))*64 + c8s;
      const size_t g1 = ((size_t)((k+1)*BT + bsg*64 + r1s))*64 + c8s;
      nR0 = *(const uint4*)&PsiR[g0];
      nI0 = *(const uint4*)&PsiI[g0];
      nR1 = *(const uint4*)&PsiR[g1];
      nI1 = *(const uint4*)&PsiI[g1];
    }
    __syncthreads();
    const int kb = k & 1;
    #pragma unroll
    for (int cc = 0; cc < 2; ++cc) {
      #pragma unroll
      for (int ct = 0; ct < 4; ++ct) {
        f32x4 xr = {0.f,0.f,0.f,0.f}, xi = {0.f,0.f,0.f,0.f};
        #pragma unroll
        for (int kk = 0; kk < 2; ++kk) {
          const half8 bRe = *(const half8*)&sP[kb][0][ct*16 + l15][l4*8 + kk*32];
          const half8 bIm = *(const half8*)&sP[kb][1][ct*16 + l15][l4*8 + kk*32];
          xr = __builtin_amdgcn_mfma_f32_16x16x32_f16(aRe[cc][kk], bRe, xr, 0, 0, 0);
          xr = __builtin_amdgcn_mfma_f32_16x16x32_f16(aMn[cc][kk], bIm, xr, 0, 0, 0);
          xi = __builtin_amdgcn_mfma_f32_16x16x32_f16(aRe[cc][kk], bIm, xi, 0, 0, 0);
          xi = __builtin_amdgcn_mfma_f32_16x16x32_f16(aIm[cc][kk], bRe, xi, 0, 0, 0);
        }
        #pragma unroll
        for (int r = 0; r < 4; ++r)
          eAcc[cc][ct][r] = fmaf(xr[r], xr[r], fmaf(xi[r], xi[r], eAcc[cc][ct][r]));
      }
    }
    if (k < 2) {
      const int nb = kb ^ 1;
      *(uint4*)&sP[nb][0][r0s][c8s] = nR0;
      *(uint4*)&sP[nb][1][r0s][c8s] = nI0;
      *(uint4*)&sP[nb][0][r1s][c8s] = nR1;
      *(uint4*)&sP[nb][1][r1s][c8s] = nI1;
    }
  }

  f16* sE = (f16*)sP;
  #pragma unroll
  for (int cc = 0; cc < 2; ++cc) {
    __syncthreads();
    #pragma unroll
    for (int ct = 0; ct < 4; ++ct)
      #pragma unroll
      for (int r = 0; r < 4; ++r)
        sE[(ct*16 + l15)*PST + w*16 + l4*4 + r] = (f16)eAcc[cc][ct][r];
    __syncthreads();
    const int cg = cgg*2 + cc;
    *(uint4*)&e16[((size_t)(bsg*64 + r0s))*1024 + cg*64 + c8s] = *(const uint4*)&sE[r0s*PST + c8s];
    *(uint4*)&e16[((size_t)(bsg*64 + r1s))*1024 + cg*64 + c8s] = *(const uint4*)&sE[r1s*PST + c8s];
  }
}

// ---------------------------------------------------------------------------
// Kernel 3: Delta-convolution (f16 e) + identity + MLP head + log_softmax.
// W1 in LDS; W2 over 48 lanes with shuffle reduce (R16's independent change).
// ---------------------------------------------------------------------------
__global__ __launch_bounds__(256) void k_head(const f16* __restrict__ e16,
    const float* __restrict__ kn, const float* __restrict__ Lam,
    const float* __restrict__ W1, const float* __restrict__ b1,
    const float* __restrict__ W2, const float* __restrict__ b2,
    float* __restrict__ out)
{
  __shared__ float sW1[4096];     // 16 KB
  __shared__ float pr[4][64];
  __shared__ float h1[4][64];
  __shared__ float lg[4][6];
  const int tid = threadIdx.x;
  const int q = tid >> 6, j = tid & 63;
  const int bt = blockIdx.x*4 + q;
  const int b = bt >> 7, t = bt & (TT-1);
  const float lam = Lam[0], om = 1.f - lam;

  for (int i = tid*4; i < 4096; i += 1024)
    *(float4*)&sW1[i] = *(const float4*)&W1[i];

  float acc = 0.f, wD = BETA_C * lam;
  const int nd = min(ND, t + 1);
  for (int D = 0; D < nd; ++D) {
    acc += wD * (float)e16[(size_t)(b*TT + t - D)*1024 + D*64 + j];
    wD *= om;
  }
  const float omt = exp2f((float)(t + 1) * log2f(om));
  acc += (BETA_C*omt + (1.f - BETA_C)) * kn[j] * (1.f/64.f);
  pr[q][j] = acc;
  __syncthreads();

  float a1 = b1[j];
  for (int dd = 0; dd < 64; ++dd) a1 = fmaf(pr[q][dd], sW1[dd*64 + j], a1);
  h1[q][j] = fmaxf(a1, 0.f);
  __syncthreads();

  if (j < 48) {                       // class c = j>>3, 8-elem partial e = j&7
    const int c = j >> 3, e = j & 7;
    float a2 = 0.f;
    #pragma unroll
    for (int u = 0; u < 8; ++u)
      a2 = fmaf(h1[q][e*8 + u], W2[(e*8 + u)*6 + c], a2);
    a2 += __shfl_xor(a2, 1);
    a2 += __shfl_xor(a2, 2);
    a2 += __shfl_xor(a2, 4);
    if (e == 0) lg[q][c] = tanhf(a2 + b2[c]);
  }
  __syncthreads();
  if (j < 6) {
    float mx = -1e30f;
    #pragma unroll
    for (int n = 0; n < 6; ++n) mx = fmaxf(mx, lg[q][n]);
    float se = 0.f;
    #pragma unroll
    for (int n = 0; n < 6; ++n) se += expf(lg[q][n] - mx);
    out[bt*6 + j] = lg[q][j] - mx - logf(se);
  }
}

// ---------------------------------------------------------------------------
extern "C" void kernel_launch(void* const* d_in, const int* in_sizes, int n_in,
                              void* d_out, int out_size, void* d_ws, size_t ws_size,
                              hipStream_t stream)
{
  const float* mod0  = (const float*)d_in[0];
  const float* Wp0   = (const float*)d_in[1];
  const float* bp0   = (const float*)d_in[2];
  const float* mod1  = (const float*)d_in[3];
  const float* Wp1   = (const float*)d_in[4];
  const float* bp1   = (const float*)d_in[5];
  const float* mod2  = (const float*)d_in[6];
  const float* Wp2   = (const float*)d_in[7];
  const float* bp2   = (const float*)d_in[8];
  const float* smask = (const float*)d_in[9];
  const float* ptab  = (const float*)d_in[11];
  const float* Uhr   = (const float*)d_in[12];
  const float* Uhi   = (const float*)d_in[13];
  const float* Uxr   = (const float*)d_in[14];
  const float* Uxi   = (const float*)d_in[15];
  const float* Lam   = (const float*)d_in[16];
  const float* Kr    = (const float*)d_in[17];
  const float* Ki    = (const float*)d_in[18];
  const float* W1    = (const float*)d_in[19];
  const float* b1    = (const float*)d_in[20];
  const float* W2    = (const float*)d_in[21];
  const float* b2    = (const float*)d_in[22];

  char* ws = (char*)d_ws;
  float* kn   = (float*)(ws);
  f16*   Cre  = (f16*)  (ws + ((size_t)1024 << 10));  // 128KB each
  f16*   Cim  = (f16*)  (ws + ((size_t)1280 << 10));
  f16*   Cmn  = (f16*)  (ws + ((size_t)1536 << 10));
  f16*   PsiR = (f16*)  (ws + ((size_t)2 << 20));     // 512KB each
  f16*   PsiI = (f16*)  (ws + ((size_t)4 << 20));
  f16*   e16  = (f16*)  (ws + ((size_t)6 << 20));     // 8.4MB
  if (ws_size < ((size_t)16 << 20)) return;

  k_front<<<320, 256, 0, stream>>>(mod0, Wp0, bp0, mod1, Wp1, bp1, mod2, Wp2, bp2,
                                   smask, ptab, Uhr, Uhi, Uxr, Uxi, Kr, Ki,
                                   PsiR, PsiI, Cre, Cim, Cmn, kn);
  k_E<<<512, 256, 0, stream>>>(Cre, Cim, Cmn, PsiR, PsiI, e16);
  k_head<<<1024, 256, 0, stream>>>(e16, kn, Lam, W1, b1, W2, b2, (float*)d_out);
}